// Round 5
// baseline (460.226 us; speedup 1.0000x reference)
//
#include <hip/hip_runtime.h>

typedef unsigned short u16;
typedef __bf16 bf16x8 __attribute__((ext_vector_type(8)));
typedef float f32x4 __attribute__((ext_vector_type(4)));

typedef __attribute__((address_space(1))) const void* as1_cvp;
typedef __attribute__((address_space(3))) void* as3_vp;

// ---------- bf16 helpers ----------
__device__ __forceinline__ float b2f(u16 u) {
  union { unsigned int i; float f; } x; x.i = ((unsigned int)u) << 16; return x.f;
}
__device__ __forceinline__ u16 f2b(float f) {
  union { float f; unsigned int i; } x; x.f = f;
  unsigned int u = x.i;
  u += 0x7fffu + ((u >> 16) & 1u);   // round-to-nearest-even
  return (u16)(u >> 16);
}

// ---------- dtype detector: flag=1 if inputs are fp32, 0 if bf16 ----------
__global__ void k_detect(const u16* __restrict__ x, int* __restrict__ flag) {
  int t = threadIdx.x;
  int sane = 0;
#pragma unroll
  for (int i = 0; i < 8; ++i) {
    u16 u = x[t * 8 + i];
    int e = (u >> 7) & 0xFF;
    sane += (u == 0 || (e >= 100 && e <= 150)) ? 1 : 0;
  }
#pragma unroll
  for (int off = 32; off >= 1; off >>= 1) sane += __shfl_xor(sane, off);
  if (t == 0) *flag = (sane < 480) ? 1 : 0;
}

// ---------- x -> bf16 row-major; no-op when inputs already bf16 ----------
__global__ void k_convert(const void* __restrict__ xin, u16* __restrict__ xb,
                          const int* __restrict__ flagp) {
  if (!*flagp) return;  // bf16 inputs: fused kernel reads raw input directly
  long i = ((long)blockIdx.x * 256 + threadIdx.x) * 4;
  float4 v = *(const float4*)((const float*)xin + i);
  u16* o = xb + i;
  o[0] = f2b(v.x); o[1] = f2b(v.y); o[2] = f2b(v.z); o[3] = f2b(v.w);
}

// ---------- W[K=512][N] -> packed bf16 B-fragments (BT[n][k] frag order) ----
// unit u = (n>>4)*16 + kc; frag is 1KB contiguous: lane ln holds 16B for
// n = (u>>4)*16 + (ln&15), k = kc*32 + (ln>>4)*8 .. +7
__global__ void k_pack_w(const void* __restrict__ W, u16* __restrict__ WP,
                         const int* __restrict__ flagp, int N) {
  const int f = *flagp;
  const int t = threadIdx.x, ln = t & 63;
  const int u = blockIdx.x * 4 + (t >> 6);          // fragment unit < N
  const int n = (u >> 4) * 16 + (ln & 15);
  const int k0 = (u & 15) * 32 + (ln >> 4) * 8;
  u16 v[8];
#pragma unroll
  for (int j = 0; j < 8; ++j) {
    long idx = (long)(k0 + j) * N + n;
    v[j] = f ? f2b(((const float*)W)[idx]) : ((const u16*)W)[idx];
  }
  u16* dst = WP + ((long)u * 64 + ln) * 8;
  ushort4 s0; s0.x = v[0]; s0.y = v[1]; s0.z = v[2]; s0.w = v[3];
  ushort4 s1; s1.x = v[4]; s1.y = v[5]; s1.z = v[6]; s1.w = v[7];
  *(ushort4*)dst = s0; *(ushort4*)(dst + 4) = s1;
}

// ---------- bias in MFMA C-fragment order, bf16, mask baked in ----------
__global__ void k_biasfrag(const int* __restrict__ rel, const void* __restrict__ table,
                           u16* __restrict__ biasFrag, const int* __restrict__ flagp) {
  int t = blockIdx.x * 256 + threadIdx.x;   // 57344 total
  int f = *flagp;
  int ln = t & 63, r2 = t >> 6;
  int tj = r2 & 7, r3 = r2 >> 3;
  int ti = r3 % 7, h = r3 / 7;
  int col = ln & 15, qrow = ln >> 4;
  int j = tj * 16 + col;
  u16 v[4];
#pragma unroll
  for (int r = 0; r < 4; ++r) {
    int i = ti * 16 + qrow * 4 + r; if (i > 97) i = 97;
    float val;
    if (j < 98) {
      int rr = rel[i * 98 + j];
      val = f ? ((const float*)table)[rr * 16 + h] : b2f(((const u16*)table)[rr * 16 + h]);
    } else {
      val = -1e30f;
    }
    v[r] = f2b(val);
  }
  ushort4 out; out.x = v[0]; out.y = v[1]; out.z = v[2]; out.w = v[3];
  *(ushort4*)(biasFrag + (long)t * 4) = out;
}

// ========== direct-fragment bf16 GEMM (proj): no LDS, no barriers ===========
// C[M][N] = A*B^T + bias from PACKED fragment operands.  128x128 block tile,
// 4 waves of 64x64.  (Verified R4.)
#define LOADSET(SA, SB, KC)                                                    \
  _Pragma("unroll") for (int mi = 0; mi < 4; ++mi) {                           \
    SA[mi][0] = *(const bf16x8*)(aB + mi * 16384 + (KC) * 1024);               \
    SA[mi][1] = *(const bf16x8*)(aB + mi * 16384 + (KC) * 1024 + 1024);        \
  }                                                                            \
  _Pragma("unroll") for (int ni = 0; ni < 4; ++ni) {                           \
    SB[ni][0] = *(const bf16x8*)(bB + ni * 16384 + (KC) * 1024);               \
    SB[ni][1] = *(const bf16x8*)(bB + ni * 16384 + (KC) * 1024 + 1024);        \
  }

#define MFMASET(SA, SB)                                                        \
  __builtin_amdgcn_s_setprio(1);                                               \
  _Pragma("unroll") for (int kk = 0; kk < 2; ++kk)                             \
  _Pragma("unroll") for (int mi = 0; mi < 4; ++mi)                             \
  _Pragma("unroll") for (int ni = 0; ni < 4; ++ni)                             \
      acc[mi][ni] = __builtin_amdgcn_mfma_f32_16x16x32_bf16(                   \
          SA[mi][kk], SB[ni][kk], acc[mi][ni], 0, 0, 0);                       \
  __builtin_amdgcn_s_setprio(0);

__global__ __launch_bounds__(256, 2) void k_gemm_direct(
    const u16* __restrict__ PA, const u16* __restrict__ PB,
    const void* __restrict__ bias, void* __restrict__ C,
    const int* __restrict__ flagp, int N, int out_follows_flag, int NBY) {
  const int f = *flagp;
  const int t = threadIdx.x, w = t >> 6, ln = t & 63;
  const int nwg = gridDim.x, cpx = nwg >> 3;
  const int wg = (blockIdx.x & 7) * cpx + (blockIdx.x >> 3);
  const long bm = (long)(wg / NBY) * 128, bn = (long)(wg % NBY) * 128;
  const int wm = w >> 1, wn = w & 1;
  const int col = ln & 15, qrow = ln >> 4;
  const char* aB = (const char*)PA + ((bm >> 4) + wm * 4) * 16384L + ln * 16;
  const char* bB = (const char*)PB + ((bn >> 4) + wn * 4) * 16384L + ln * 16;
  float bv[4];
#pragma unroll
  for (int ni = 0; ni < 4; ++ni) {
    long c = bn + wn * 64 + ni * 16 + col;
    bv[ni] = f ? ((const float*)bias)[c] : b2f(((const u16*)bias)[c]);
  }
  f32x4 acc[4][4] = {};
  bf16x8 aX[4][2], bX[4][2], aY[4][2], bY[4][2];
  LOADSET(aX, bX, 0)
  LOADSET(aY, bY, 2)
#pragma unroll
  for (int kc = 0; kc < 16; kc += 4) {
    MFMASET(aX, bX)
    if (kc + 4 < 16) { LOADSET(aX, bX, kc + 4) }
    MFMASET(aY, bY)
    if (kc + 6 < 16) { LOADSET(aY, bY, kc + 6) }
  }
  const int of = out_follows_flag ? f : 0;
#pragma unroll
  for (int mi = 0; mi < 4; ++mi)
#pragma unroll
    for (int ni = 0; ni < 4; ++ni)
#pragma unroll
      for (int r = 0; r < 4; ++r) {
        long row = bm + wm * 64 + mi * 16 + qrow * 4 + r;
        long c = bn + wn * 64 + ni * 16 + col;
        float v = acc[mi][ni][r] + bv[ni];
        if (of) ((float*)C)[row * N + c] = v;
        else    ((u16*)C)[row * N + c] = f2b(v);
      }
}

// ========== FUSED qkv-projection + window attention ==========
// One block per (b,h), 4 waves.  Computes QKV = x[b] @ Wqkv[:, head h slice]
// (112x96 mini-GEMM, A per-lane from row-major bf16 x, B from packed wqkvP),
// writes Q/K/V into LDS, then runs the verified attention code and stores the
// output packed (fragment order) for the proj GEMM.  qkv intermediate never
// touches global memory (saves ~300MB HBM round trip vs separate kernels).
#define LOADQ(AS0, AS1, BS, KC) do {                                           \
    AS0 = *(const bf16x8*)(a0p + (KC) * 64);                                   \
    AS1 = *(const bf16x8*)(a1p + (KC) * 64);                                   \
    _Pragma("unroll") for (int nt = 0; nt < 6; ++nt)                           \
      BS[nt] = *(const bf16x8*)(bB[nt] + (KC) * 1024);                         \
  } while (0)

#define MFMAQ(AS0, AS1, BS)                                                    \
  __builtin_amdgcn_s_setprio(1);                                               \
  _Pragma("unroll") for (int nt = 0; nt < 6; ++nt)                             \
    acc[0][nt] = __builtin_amdgcn_mfma_f32_16x16x32_bf16(AS0, BS[nt],          \
                                                         acc[0][nt], 0, 0, 0); \
  if (has1) {                                                                  \
    _Pragma("unroll") for (int nt = 0; nt < 6; ++nt)                           \
      acc[1][nt] = __builtin_amdgcn_mfma_f32_16x16x32_bf16(AS1, BS[nt],        \
                                                          acc[1][nt], 0, 0, 0);\
  }                                                                            \
  __builtin_amdgcn_s_setprio(0);

__global__ __launch_bounds__(256, 3) void k_fused(
    const u16* __restrict__ x_raw, const u16* __restrict__ x_conv,
    const u16* __restrict__ WP, const void* __restrict__ qkvb,
    const u16* __restrict__ biasFrag, u16* __restrict__ attnp,
    const int* __restrict__ flagp) {
  __shared__ __align__(16) u16 Qs[112 * 32];     // aliased as Os after compute
  __shared__ __align__(16) u16 Ks[128 * 32];
  __shared__ __align__(16) u16 Vt[32 * 136];
  __shared__ __align__(16) u16 Ps[4][16 * 136];  // per-wave slot
  const int f = *flagp;
  const u16* X = f ? x_conv : x_raw;
  const int t = threadIdx.x, w = t >> 6, ln = t & 63;
  // XCD swizzle: all 16 h-blocks of one b land on the same XCD, back-to-back,
  // so the 98KB x panel is fetched from HBM once and L2-served 15 times.
  const int raw = blockIdx.x;
  const int xcd = raw & 7, slot = raw >> 3;
  const int b = xcd + 8 * (slot >> 4), h = slot & 15;
  const long r0 = (long)b * 98;
  const int col = ln & 15, qrow = ln >> 4;
  const int has1 = (w < 3);

  // zero pads: Ks rows 112..127 (never written by QKV phase), Vt cols 98..135
  *(unsigned int*)&Ks[112 * 32 + t * 2] = 0u;
  for (int z = t; z < 32 * 19; z += 256) {
    int d = z / 19, q = z % 19;
    *(unsigned int*)&Vt[d * 136 + 98 + q * 2] = 0u;
  }

  // ---------------- QKV mini-GEMM: rows r0+ti*16.., cols = head h's 96 ------
  // A frag (m-tile ti): lane ln reads 16B of row R = r0+ti*16+(ln&15),
  //   k-range kc*32 + (ln>>4)*8 .. +7  (row-major bf16 x, 1KB/row)
  long R0 = r0 + w * 16 + (ln & 15);        if (R0 > 50175) R0 = 50175;
  long R1 = r0 + (w + 4) * 16 + (ln & 15);  if (R1 > 50175) R1 = 50175;
  const char* a0p = (const char*)X + R0 * 1024 + (qrow << 4);
  const char* a1p = (const char*)X + R1 * 1024 + (qrow << 4);
  // B frags from packed W: n-groups {2h,2h+1} (q), {32+2h,33+2h} (k),
  // {64+2h,65+2h} (v); frag (g,kc) at byte (g*16+kc)*1024 + ln*16
  const char* wb = (const char*)WP + ln * 16;
  const char* bB[6];
  bB[0] = wb + (long)(2 * h) * 16384;       bB[1] = wb + (long)(2 * h + 1) * 16384;
  bB[2] = wb + (long)(32 + 2 * h) * 16384;  bB[3] = wb + (long)(33 + 2 * h) * 16384;
  bB[4] = wb + (long)(64 + 2 * h) * 16384;  bB[5] = wb + (long)(65 + 2 * h) * 16384;

  f32x4 acc[2][6] = {};
  bf16x8 aX0, aX1, bXv[6], aY0, aY1, bYv[6];
  LOADQ(aX0, aX1, bXv, 0);
  LOADQ(aY0, aY1, bYv, 1);
#pragma unroll
  for (int kc = 0; kc < 16; kc += 2) {
    MFMAQ(aX0, aX1, bXv)
    if (kc + 2 < 16) LOADQ(aX0, aX1, bXv, kc + 2);
    MFMAQ(aY0, aY1, bYv)
    if (kc + 3 < 16) LOADQ(aY0, aY1, bYv, kc + 3);
  }
  // qkv bias per n-tile (zeros in practice, kept general)
  float qb[6];
  {
    const int nb0 = h * 32;
    const int nbs[6] = {nb0, nb0 + 16, 512 + nb0, 528 + nb0, 1024 + nb0, 1040 + nb0};
#pragma unroll
    for (int nt = 0; nt < 6; ++nt) {
      int n = nbs[nt] + col;
      qb[nt] = f ? ((const float*)qkvb)[n] : b2f(((const u16*)qkvb)[n]);
    }
  }
  // scatter C-frags to LDS: Q -> Qs[i][c], K -> Ks[j][c], V -> Vt[c][i]
#pragma unroll
  for (int tt = 0; tt < 2; ++tt) {
    if (tt == 1 && !has1) break;
    const int ti = w + tt * 4;
#pragma unroll
    for (int nt = 0; nt < 6; ++nt)
#pragma unroll
      for (int r = 0; r < 4; ++r) {
        const int i = ti * 16 + qrow * 4 + r;
        const u16 hv = f2b(acc[tt][nt][r] + qb[nt]);
        if (nt < 2)      Qs[i * 32 + nt * 16 + col] = hv;
        else if (nt < 4) Ks[i * 32 + (nt - 2) * 16 + col] = hv;
        else if (i < 98) Vt[((nt - 4) * 16 + col) * 136 + i] = hv;
      }
  }
  __syncthreads();

  // ---------------- attention (verified code path) ----------------
  const float scale = 0.17677669529663687f;  // 32^-0.5
  u16* Psw = &Ps[w][0];
  f32x4 o[2][2] = {{{0.f,0.f,0.f,0.f},{0.f,0.f,0.f,0.f}},{{0.f,0.f,0.f,0.f},{0.f,0.f,0.f,0.f}}};
  for (int tt = 0; tt < 2; ++tt) {
    const int ti = w + tt * 4;
    if (ti >= 7) break;
    const u16* bp = biasFrag + ((long)((h * 7 + ti) * 8) * 64 + ln) * 4;
    ushort4 bfv[8];
#pragma unroll
    for (int tj = 0; tj < 8; ++tj) bfv[tj] = *(const ushort4*)(bp + tj * 256);
    bf16x8 aq = *(const bf16x8*)&Qs[(ti * 16 + col) * 32 + qrow * 8];
    f32x4 s[8];
#pragma unroll
    for (int tj = 0; tj < 8; ++tj) {
      bf16x8 bk = *(const bf16x8*)&Ks[(tj * 16 + col) * 32 + qrow * 8];
      f32x4 z = {0.f, 0.f, 0.f, 0.f};
      s[tj] = __builtin_amdgcn_mfma_f32_16x16x32_bf16(aq, bk, z, 0, 0, 0);
    }
#pragma unroll
    for (int r = 0; r < 4; ++r) {
      float vals[8]; float m = -1e30f;
#pragma unroll
      for (int tj = 0; tj < 8; ++tj) {
        u16 bb = (r == 0) ? bfv[tj].x : (r == 1) ? bfv[tj].y : (r == 2) ? bfv[tj].z : bfv[tj].w;
        float v = fmaf(s[tj][r], scale, b2f(bb));
        vals[tj] = v; m = fmaxf(m, v);
      }
#pragma unroll
      for (int off = 1; off < 16; off <<= 1) m = fmaxf(m, __shfl_xor(m, off));
      float sum = 0.f;
#pragma unroll
      for (int tj = 0; tj < 8; ++tj) { vals[tj] = __expf(vals[tj] - m); sum += vals[tj]; }
#pragma unroll
      for (int off = 1; off < 16; off <<= 1) sum += __shfl_xor(sum, off);
      float inv = 1.f / sum;
      const int rt = qrow * 4 + r;
#pragma unroll
      for (int tj = 0; tj < 8; ++tj)
        Psw[rt * 136 + tj * 16 + col] = f2b(vals[tj] * inv);
    }
#pragma unroll
    for (int ks = 0; ks < 4; ++ks) {
      bf16x8 ap  = *(const bf16x8*)&Psw[col * 136 + ks * 32 + qrow * 8];
      bf16x8 bv0 = *(const bf16x8*)&Vt[col * 136 + ks * 32 + qrow * 8];
      bf16x8 bv1 = *(const bf16x8*)&Vt[(16 + col) * 136 + ks * 32 + qrow * 8];
      o[tt][0] = __builtin_amdgcn_mfma_f32_16x16x32_bf16(ap, bv0, o[tt][0], 0, 0, 0);
      o[tt][1] = __builtin_amdgcn_mfma_f32_16x16x32_bf16(ap, bv1, o[tt][1], 0, 0, 0);
    }
  }
  __syncthreads();   // everyone done reading Qs -> reuse as output staging
  u16* Os = Qs;
#pragma unroll
  for (int tt = 0; tt < 2; ++tt) {
    const int ti = w + tt * 4;
    if (ti >= 7) continue;
#pragma unroll
    for (int r = 0; r < 4; ++r) {
      const int i = ti * 16 + qrow * 4 + r;
      if (i < 98) {
        Os[i * 32 + col]      = f2b(o[tt][0][r]);
        Os[i * 32 + 16 + col] = f2b(o[tt][1][r]);
      }
    }
  }
  __syncthreads();
  // packed store: element (r = b*98+i, k = h*32 + o*8 + j) -> fragment layout
  for (int idx = t; idx < 392; idx += 256) {
    int i = idx >> 2, oo = idx & 3;
    long r = (long)b * 98 + i;
    u16* dst = attnp + ((r >> 4) * 16 + h) * 512 + ((r & 15) + (oo << 4)) * 8;
    const u16* src = &Os[i * 32 + oo * 8];
    *(ushort4*)dst = *(const ushort4*)src;
    *(ushort4*)(dst + 4) = *(const ushort4*)(src + 4);
  }
}

extern "C" void kernel_launch(void* const* d_in, const int* in_sizes, int n_in,
                              void* d_out, int out_size, void* d_ws, size_t ws_size,
                              hipStream_t stream) {
  (void)in_sizes; (void)n_in; (void)out_size; (void)ws_size;
  char* p = (char*)d_ws;
  u16* xb       = (u16*)p;  p += 50176L * 512 * 2;   // 51,380,224
  u16* attnbuf  = (u16*)p;  p += 50176L * 512 * 2;   // 51,380,224 (packed)
  u16* wqkvP    = (u16*)p;  p += 1536L * 512 * 2;    // 1,572,864
  u16* wprojP   = (u16*)p;  p += 512L * 512 * 2;     // 524,288
  u16* biasFrag = (u16*)p;  p += 57344L * 4 * 2;     // 458,752
  int* flagp    = (int*)p;

  k_detect<<<1, 64, 0, stream>>>((const u16*)d_in[0], flagp);
  k_convert<<<25088, 256, 0, stream>>>(d_in[0], xb, flagp);
  k_pack_w<<<384, 256, 0, stream>>>(d_in[1], wqkvP, flagp, 1536);
  k_pack_w<<<128, 256, 0, stream>>>(d_in[3], wprojP, flagp, 512);
  k_biasfrag<<<224, 256, 0, stream>>>((const int*)d_in[6], d_in[5], biasFrag, flagp);
  // fused qkv-projection + attention -> attnbuf (packed), qkv never in HBM
  k_fused<<<dim3(8192), 256, 0, stream>>>((const u16*)d_in[0], xb, wqkvP, d_in[2],
                                          biasFrag, attnbuf, flagp);
  // out = attn @ proj_w + proj_b   [50176 x 512], 392x4 tiles of 128^2
  k_gemm_direct<<<dim3(392 * 4), 256, 0, stream>>>(attnbuf, wprojP, d_in[4], d_out,
                                                   flagp, 512, 1, 4);
}